// Round 7
// baseline (357.695 us; speedup 1.0000x reference)
//
#include <hip/hip_runtime.h>
#include <stdint.h>

// Problem constants
#define B_    64
#define N_    512
#define DIM_  256
#define H_    8
#define DH_   64
#define INNER_ 512

typedef __attribute__((ext_vector_type(8))) short bf16x8;
typedef __attribute__((ext_vector_type(4))) float f32x4;
typedef __attribute__((ext_vector_type(4))) short s16x4;

typedef const __attribute__((address_space(1))) void* gas_ptr;
typedef __attribute__((address_space(3))) void* las_ptr;

__device__ __forceinline__ short f2bf(float f) {
  unsigned int u = __float_as_uint(f);
  u += 0x7fffu + ((u >> 16) & 1u);          // RNE
  return (short)(u >> 16);
}
__device__ __forceinline__ float bf2f(short s) {
  return __uint_as_float(((unsigned int)(unsigned short)s) << 16);
}
__device__ __forceinline__ void cp16(const void* g, void* l) {
  __builtin_amdgcn_global_load_lds((gas_ptr)g, (las_ptr)l, 16, 0, 0);
}
__device__ __forceinline__ f32x4 mfma16(bf16x8 a, bf16x8 b, f32x4 c) {
  return __builtin_amdgcn_mfma_f32_16x16x32_bf16(a, b, c, 0, 0, 0);
}

// ---------------------------------------------------------------------------
// Prep: fp32 -> bf16 edge conversions (+ scaled bias copy, float mask).
// ---------------------------------------------------------------------------
#define PREP_WT1  (2048 * 256)
#define PREP_WOT  (256 * 512)
#define PREP_X    (32768 * 256)
#define PREP_BIAS (8 * 512 * 512)
#define PREP_MASK (64 * 512)
#define PREP_TOT  (PREP_WT1 + PREP_WOT + PREP_X + PREP_BIAS + PREP_MASK)

__global__ void prep_k(const float* __restrict__ x,
                       const float* __restrict__ Wq, const float* __restrict__ Wkv,
                       const float* __restrict__ Wg, const float* __restrict__ Wo,
                       const float* __restrict__ bias, const int* __restrict__ mask,
                       short* __restrict__ Wt1, short* __restrict__ WoT,
                       short* __restrict__ xb, float* __restrict__ biasS,
                       float* __restrict__ maskF)
{
  const int idx = blockIdx.x * 256 + threadIdx.x;
  if (idx < PREP_WT1) {
    const int n = idx >> 8, k = idx & 255;
    float v;
    if (n < 512)        v = Wq[k * 512 + n];
    else if (n < 1536)  v = Wkv[k * 1024 + (n - 512)];   // K cols then V cols
    else                v = Wg[k * 512 + (n - 1536)];
    Wt1[idx] = f2bf(v);
  } else if (idx < PREP_WT1 + PREP_WOT) {
    const int j = idx - PREP_WT1;
    const int n = j >> 9, k = j & 511;
    WoT[j] = f2bf(Wo[k * 256 + n]);
  } else if (idx < PREP_WT1 + PREP_WOT + PREP_X) {
    const int j = idx - (PREP_WT1 + PREP_WOT);
    xb[j] = f2bf(x[j]);
  } else if (idx < PREP_WT1 + PREP_WOT + PREP_X + PREP_BIAS) {
    const int j = idx - (PREP_WT1 + PREP_WOT + PREP_X);
    biasS[j] = bias[j] * 1.4426950408889634f;            // coalesced scaled copy
  } else if (idx < PREP_TOT) {
    const int j = idx - (PREP_WT1 + PREP_WOT + PREP_X + PREP_BIAS);
    maskF[j] = mask[j] ? 1.0f : 0.0f;
  }
}

// ---------------------------------------------------------------------------
// GEMM1: C = xb[32768,256] @ Wt1^T  (N=2048 fused Q|K|V|G), all bf16.
// Orientation per region:
//   V region:   acc = mfma(af, bfv)  -> lane: 4 consecutive tokens n, col d
//               -> s16x4 along n into Vt[d][n].
//   Q/K/G:      acc = mfma(bfv, af)  -> lane: 4 consecutive cols c, row token
//               -> s16x4 along d/c, row-major (vector stores, no transpose).
// ---------------------------------------------------------------------------
__global__ __launch_bounds__(256, 2) void gemm_qkvg(
    const short* __restrict__ X, const short* __restrict__ Wt,
    const float* __restrict__ bg,
    short* __restrict__ Q, short* __restrict__ Kb,
    short* __restrict__ Vt, short* __restrict__ G)
{
  __shared__ __align__(16) short As[128 * 32];
  __shared__ __align__(16) short Bs[128 * 32];
  const int tid = threadIdx.x;
  const int w = tid >> 6, lane = tid & 63;
  const int m = lane & 15, q = lane >> 4;
  const int n0 = blockIdx.x * 128, m0 = blockIdx.y * 128;
  const int ric = lane >> 2, cslot = lane & 3;
  const int csw = cslot ^ ((ric >> 1) & 3);
  const int wr = (w >> 1) * 64, wc = (w & 1) * 64;
  const int rsw = (m >> 1) & 3;
  const int region = blockIdx.x >> 2;           // 0=Q 1=K 2=V 3=G
  f32x4 acc[4][4] = {};

  if (region == 2) {                            // ---- V path ----
    for (int k0 = 0; k0 < DIM_; k0 += 32) {
      __syncthreads();
#pragma unroll
      for (int s = 0; s < 2; ++s) {
        const int rr = w * 32 + s * 16;
        cp16(X  + (size_t)(m0 + rr + ric) * DIM_ + (k0 + csw * 8), &As[rr * 32]);
        cp16(Wt + (size_t)(n0 + rr + ric) * DIM_ + (k0 + csw * 8), &Bs[rr * 32]);
      }
      __syncthreads();
      bf16x8 af[4], bfv[4];
#pragma unroll
      for (int t = 0; t < 4; ++t) {
        af[t]  = *(const bf16x8*)&As[(wr + t * 16 + m) * 32 + ((q ^ rsw) * 8)];
        bfv[t] = *(const bf16x8*)&Bs[(wc + t * 16 + m) * 32 + ((q ^ rsw) * 8)];
      }
#pragma unroll
      for (int ti = 0; ti < 4; ++ti)
#pragma unroll
        for (int tj = 0; tj < 4; ++tj)
          acc[ti][tj] = mfma16(af[ti], bfv[tj], acc[ti][tj]);
    }
    const int cb = (n0 & 511) + wc;
#pragma unroll
    for (int ti = 0; ti < 4; ++ti) {
      const int mgb = m0 + wr + ti * 16 + q * 4;     // token base (4 rows)
      const int b = mgb >> 9, n = mgb & 511;
#pragma unroll
      for (int tj = 0; tj < 4; ++tj) {
        const int c = cb + tj * 16 + m;
        const int h = c >> 6, d = c & 63;
        s16x4 st;
#pragma unroll
        for (int r = 0; r < 4; ++r) st[r] = f2bf(acc[ti][tj][r]);
        *(s16x4*)&Vt[((size_t)(b * 8 + h) * 64 + d) * 512 + n] = st;
      }
    }
  } else {                                      // ---- Q/K/G path (transposed) ----
    for (int k0 = 0; k0 < DIM_; k0 += 32) {
      __syncthreads();
#pragma unroll
      for (int s = 0; s < 2; ++s) {
        const int rr = w * 32 + s * 16;
        cp16(X  + (size_t)(m0 + rr + ric) * DIM_ + (k0 + csw * 8), &As[rr * 32]);
        cp16(Wt + (size_t)(n0 + rr + ric) * DIM_ + (k0 + csw * 8), &Bs[rr * 32]);
      }
      __syncthreads();
      bf16x8 af[4], bfv[4];
#pragma unroll
      for (int t = 0; t < 4; ++t) {
        af[t]  = *(const bf16x8*)&As[(wr + t * 16 + m) * 32 + ((q ^ rsw) * 8)];
        bfv[t] = *(const bf16x8*)&Bs[(wc + t * 16 + m) * 32 + ((q ^ rsw) * 8)];
      }
#pragma unroll
      for (int ti = 0; ti < 4; ++ti)
#pragma unroll
        for (int tj = 0; tj < 4; ++tj)
          acc[ti][tj] = mfma16(bfv[tj], af[ti], acc[ti][tj]);   // swapped
    }
    const int cb2 = (n0 & 511) + wc;
#pragma unroll
    for (int ti = 0; ti < 4; ++ti) {
      const int token = m0 + wr + ti * 16 + m;
      const int b = token >> 9, n = token & 511;
#pragma unroll
      for (int tj = 0; tj < 4; ++tj) {
        const int c = cb2 + tj * 16 + q * 4;         // 4 consecutive cols
        if (region == 0) {
          const int h = c >> 6, d = c & 63;
          s16x4 st;
#pragma unroll
          for (int r = 0; r < 4; ++r) st[r] = f2bf(acc[ti][tj][r]);
          *(s16x4*)&Q[((size_t)(b * 8 + h) * 512 + n) * 64 + d] = st;
        } else if (region == 1) {
          const int h = c >> 6, d = c & 63;
          s16x4 st;
#pragma unroll
          for (int r = 0; r < 4; ++r) st[r] = f2bf(acc[ti][tj][r]);
          *(s16x4*)&Kb[((size_t)(b * 8 + h) * 512 + n) * 64 + d] = st;
        } else {                                     // G = x@Wg + bg
          const f32x4 bg4 = *(const f32x4*)&bg[c];
          s16x4 st;
#pragma unroll
          for (int r = 0; r < 4; ++r) st[r] = f2bf(acc[ti][tj][r] + bg4[r]);
          *(s16x4*)&G[(size_t)token * 512 + c] = st;
        }
      }
    }
  }
}

// ---------------------------------------------------------------------------
// Attention, flash-style. S^T = K·Q^T (P writes vectorized), O^T = V^T·P
// (gate RMW vectorized, per-lane-uniform 1/l). K/V double-buffered in LDS via
// global_load_lds; P per-wave reused per i-tile. No-max exp2 softmax; l from
// the stored truncated-bf16 P.
// ---------------------------------------------------------------------------
__global__ __launch_bounds__(256, 4) void attn_k(
    const short* __restrict__ Q, const short* __restrict__ K,
    const short* __restrict__ Vt, const float* __restrict__ biasS,
    const float* __restrict__ maskF, short* __restrict__ G)
{
  __shared__ __align__(16) short Ks[2][64 * 64];   // [j][d], xor-swizzled 8-chunks
  __shared__ __align__(16) short Vs[2][64 * 64];   // [d][j], xor-swizzled
  __shared__ __align__(16) short Pall[4][16 * 64]; // per-wave, reused per i-tile
  const int tid = threadIdx.x;
  const int w = tid >> 6, lane = tid & 63;
  const int m = lane & 15, q = lane >> 4;
  const int m7 = m & 7;
  const int b = blockIdx.x, iq = blockIdx.y, h = blockIdx.z;
  const int i0w = iq * 128 + w * 32;               // this wave's first Q row
  const size_t bh = (size_t)b * 8 + h;
  const short* Qp = Q + (bh * 512 + i0w) * 64;
  const short* Kp = K + bh * 512 * 64;
  const short* Vp = Vt + bh * 64 * 512;
  const float* mkp = maskF + b * 512;
  short* Ps = Pall[w];

  const int srow = lane >> 3;                      // staging row in 8-row group
  const int gchunk = (lane & 7) ^ (srow & 7);      // global 8-short chunk to fetch

  // Q frags: lane holds Q[i = it*16+m][d = q*8 ..]
  bf16x8 qf[2][2];
#pragma unroll
  for (int it = 0; it < 2; ++it) {
    qf[it][0] = *(const bf16x8*)&Qp[(it * 16 + m) * 64 + q * 8];
    qf[it][1] = *(const bf16x8*)&Qp[(it * 16 + m) * 64 + 32 + q * 8];
  }
  float miF[2];
#pragma unroll
  for (int it = 0; it < 2; ++it) miF[it] = mkp[i0w + it * 16 + m];

  // stage chunk 0
#pragma unroll
  for (int s2 = 0; s2 < 2; ++s2) {
    const int rr = w * 16 + s2 * 8;
    cp16(Kp + (size_t)(rr + srow) * 64 + gchunk * 8, &Ks[0][rr * 64]);
    cp16(Vp + (size_t)(rr + srow) * 512 + gchunk * 8, &Vs[0][rr * 64]);
  }
  f32x4 o[2][4] = {};                              // o^T: row d, col i
  float l[2] = {0.f, 0.f};
  __syncthreads();                                 // chunk 0 staged

  const float SCL = 0.125f * 1.4426950408889634f;  // scale * log2(e)
  for (int c = 0; c < 8; ++c) {
    const int p = c & 1;
    if (c < 7) {                                   // prefetch next chunk
      const int jn = (c + 1) * 64;
#pragma unroll
      for (int s2 = 0; s2 < 2; ++s2) {
        const int rr = w * 16 + s2 * 8;
        cp16(Kp + (size_t)(jn + rr + srow) * 64 + gchunk * 8, &Ks[p ^ 1][rr * 64]);
        cp16(Vp + (size_t)(rr + srow) * 512 + jn + gchunk * 8, &Vs[p ^ 1][rr * 64]);
      }
    }
    // mask (f32x4 per jt): j = c*64 + jt*16 + q*4 + r
    f32x4 mjf[4];
#pragma unroll
    for (int jt = 0; jt < 4; ++jt)
      mjf[jt] = *(const f32x4*)&mkp[c * 64 + jt * 16 + q * 4];

    // S^T: lane holds S[i = it*16+m][j = c*64 + jt*16 + q*4 + r]
    f32x4 s[2][4];
#pragma unroll
    for (int jt = 0; jt < 4; ++jt) {
      const bf16x8 ka = *(const bf16x8*)&Ks[p][(jt * 16 + m) * 64 + ((q ^ m7) * 8)];
      const bf16x8 kb = *(const bf16x8*)&Ks[p][(jt * 16 + m) * 64 + (((4 + q) ^ m7) * 8)];
#pragma unroll
      for (int it = 0; it < 2; ++it) {
        f32x4 a = {};
        a = mfma16(ka, qf[it][0], a);
        s[it][jt] = mfma16(kb, qf[it][1], a);
      }
    }
#pragma unroll
    for (int it = 0; it < 2; ++it) {
      // bias (fp32, prescaled by log2e, [h][i][j] layout)
      const float* bp = biasS + ((size_t)h * 512 + i0w + it * 16 + m) * 512 + c * 64;
      f32x4 bv[4];
#pragma unroll
      for (int jt = 0; jt < 4; ++jt)
        bv[jt] = *(const f32x4*)&bp[jt * 16 + q * 4];
      // softmax terms -> packed b64 P writes (4 consecutive j per lane)
#pragma unroll
      for (int jt = 0; jt < 4; ++jt) {
        s16x4 st;
#pragma unroll
        for (int r = 0; r < 4; ++r) {
          const float v = fmaf(s[it][jt][r], SCL, bv[jt][r]);
          float e = exp2f(v) * mjf[jt][r];
          e = (miF[it] != 0.0f) ? e : 1.0f;        // fully-masked row -> uniform
          const unsigned u = __float_as_uint(e);
          st[r] = (short)(u >> 16);                // trunc pack
          l[it] += __uint_as_float(u & 0xffff0000u); // == stored P
        }
        *(s16x4*)&Ps[m * 64 + (((jt * 2 + (q >> 1)) ^ m7) * 8) + (q & 1) * 4] = st;
      }
      // PV (transposed): o^T += mfma(A = V^T rows d, B = P rows i)
      const bf16x8 pa = *(const bf16x8*)&Ps[m * 64 + ((q ^ m7) * 8)];
      const bf16x8 pb = *(const bf16x8*)&Ps[m * 64 + (((4 + q) ^ m7) * 8)];
#pragma unroll
      for (int dt = 0; dt < 4; ++dt) {
        const bf16x8 va = *(const bf16x8*)&Vs[p][(dt * 16 + m) * 64 + ((q ^ m7) * 8)];
        const bf16x8 vb = *(const bf16x8*)&Vs[p][(dt * 16 + m) * 64 + (((4 + q) ^ m7) * 8)];
        o[it][dt] = mfma16(va, pa, o[it][dt]);
        o[it][dt] = mfma16(vb, pb, o[it][dt]);
      }
    }
    __syncthreads();  // Ks/Vs[p] reads done; prefetch (p^1) drained
  }

  // ---- epilogue: reduce l over q-lanes; lane's rows all share col i=m ----
  float linv[2];
#pragma unroll
  for (int it = 0; it < 2; ++it) {
    float t = l[it];
    t += __shfl_xor(t, 16, 64);
    t += __shfl_xor(t, 32, 64);
    linv[it] = 1.0f / t;                           // for row i = it*16 + m
  }
  const int colb = h * 64;
#pragma unroll
  for (int it = 0; it < 2; ++it) {
    const int i = i0w + it * 16 + m;               // o^T col (lane-uniform per it)
#pragma unroll
    for (int dt = 0; dt < 4; ++dt) {
      const int cbase = colb + dt * 16 + q * 4;    // 4 consecutive d
      const size_t addr = ((size_t)b * 512 + i) * 512 + cbase;
      const s16x4 g4 = *(const s16x4*)&G[addr];
      s16x4 st;
#pragma unroll
      for (int r = 0; r < 4; ++r)
        st[r] = f2bf(o[it][dt][r] * linv[it] * bf2f(g4[r]));
      *(s16x4*)&G[addr] = st;
    }
  }
}

// ---------------------------------------------------------------------------
// GEMM3: out = OG[32768,512] @ Wo + bo, fp32 output, transposed orientation
// -> f32x4 stores (lane holds 4 consecutive out cols).
// ---------------------------------------------------------------------------
__global__ __launch_bounds__(256, 2) void gemm_og(
    const short* __restrict__ A, const short* __restrict__ Bt,
    const float* __restrict__ bo, float* __restrict__ out)
{
  __shared__ __align__(16) short As[128 * 32];
  __shared__ __align__(16) short Bs[128 * 32];
  const int tid = threadIdx.x;
  const int w = tid >> 6, lane = tid & 63;
  const int m = lane & 15, q = lane >> 4;
  const int n0 = blockIdx.x * 128, m0 = blockIdx.y * 128;
  const int ric = lane >> 2, cslot = lane & 3;
  const int csw = cslot ^ ((ric >> 1) & 3);
  const int wr = (w >> 1) * 64, wc = (w & 1) * 64;
  const int rsw = (m >> 1) & 3;
  f32x4 acc[4][4] = {};
  for (int k0 = 0; k0 < INNER_; k0 += 32) {
    __syncthreads();
#pragma unroll
    for (int s = 0; s < 2; ++s) {
      const int rr = w * 32 + s * 16;
      cp16(A  + (size_t)(m0 + rr + ric) * INNER_ + (k0 + csw * 8), &As[rr * 32]);
      cp16(Bt + (size_t)(n0 + rr + ric) * INNER_ + (k0 + csw * 8), &Bs[rr * 32]);
    }
    __syncthreads();
    bf16x8 af[4], bfv[4];
#pragma unroll
    for (int t = 0; t < 4; ++t) {
      af[t]  = *(const bf16x8*)&As[(wr + t * 16 + m) * 32 + ((q ^ rsw) * 8)];
      bfv[t] = *(const bf16x8*)&Bs[(wc + t * 16 + m) * 32 + ((q ^ rsw) * 8)];
    }
#pragma unroll
    for (int ti = 0; ti < 4; ++ti)
#pragma unroll
      for (int tj = 0; tj < 4; ++tj)
        acc[ti][tj] = mfma16(bfv[tj], af[ti], acc[ti][tj]);   // transposed
  }
#pragma unroll
  for (int ti = 0; ti < 4; ++ti) {
    const int row = m0 + wr + ti * 16 + m;
#pragma unroll
    for (int tj = 0; tj < 4; ++tj) {
      const int c = n0 + wc + tj * 16 + q * 4;     // 4 consecutive cols
      const f32x4 bo4 = *(const f32x4*)&bo[c];
      f32x4 st;
#pragma unroll
      for (int r = 0; r < 4; ++r) st[r] = acc[ti][tj][r] + bo4[r];
      *(f32x4*)&out[(size_t)row * 256 + c] = st;
    }
  }
}

// ---------------------------------------------------------------------------
extern "C" void kernel_launch(void* const* d_in, const int* in_sizes, int n_in,
                              void* d_out, int out_size, void* d_ws, size_t ws_size,
                              hipStream_t stream)
{
  (void)in_sizes; (void)n_in; (void)out_size; (void)ws_size;
  const float* x    = (const float*)d_in[0];
  const int*   mask = (const int*)d_in[1];
  const float* bias = (const float*)d_in[2];
  const float* Wq   = (const float*)d_in[3];
  const float* Wkv  = (const float*)d_in[4];
  const float* Wo   = (const float*)d_in[5];
  const float* bo   = (const float*)d_in[6];
  const float* Wg   = (const float*)d_in[7];
  const float* bg   = (const float*)d_in[8];
  float* out = (float*)d_out;

  char* ws = (char*)d_ws;
  size_t off = 0;
  short* Wt1   = (short*)(ws + off); off += (size_t)2048 * 256 * 2;         // 1.0 MiB
  short* WoT   = (short*)(ws + off); off += (size_t)256 * 512 * 2;          // 0.25 MiB
  short* xb    = (short*)(ws + off); off += (size_t)32768 * 256 * 2;        // 16 MiB
  short* Qb    = (short*)(ws + off); off += (size_t)B_ * H_ * N_ * DH_ * 2; // 32 MiB
  short* Kb    = (short*)(ws + off); off += (size_t)B_ * H_ * N_ * DH_ * 2; // 32 MiB
  short* Vt    = (short*)(ws + off); off += (size_t)B_ * H_ * DH_ * N_ * 2; // 32 MiB
  short* G     = (short*)(ws + off); off += (size_t)B_ * N_ * INNER_ * 2;   // 32 MiB
  float* biasS = (float*)(ws + off); off += (size_t)H_ * N_ * N_ * 4;       // 8 MiB
  float* maskF = (float*)(ws + off); off += (size_t)B_ * N_ * 4;            // 128 KiB

  prep_k<<<(PREP_TOT + 255) / 256, 256, 0, stream>>>(x, Wq, Wkv, Wg, Wo, bias, mask,
                                                     Wt1, WoT, xb, biasS, maskF);
  gemm_qkvg<<<dim3(16, 256), 256, 0, stream>>>(xb, Wt1, bg, Qb, Kb, Vt, G);
  attn_k<<<dim3(64, 4, 8), 256, 0, stream>>>(Qb, Kb, Vt, biasS, maskF, G);
  gemm_og<<<dim3(2, 256), 256, 0, stream>>>(G, WoT, bo, out);
}